// Round 7
// baseline (187.238 us; speedup 1.0000x reference)
//
#include <hip/hip_runtime.h>

#define S 256
#define BIGE 1.0e9f              // BIG in E(log2) domain. 1e9 is a multiple of 64=ulp(1e9),
                                 // and |cE - log2(3)| < 2, so BIGE + cE - log2(s) rounds back
                                 // to exactly BIGE -> pre-start cells stay BIGE with NO masks.
#define L2E 1.44269504088896340736f   // log2(e)
#define LN2 0.69314718055994530942f

// Raw HW transcendentals: v_exp_f32 = 2^x, v_log_f32 = log2(x).
#define EXP2F(x) __builtin_amdgcn_exp2f(x)
#define LOG2F(x) __builtin_amdgcn_logf(x)

// One wave (64 threads) per batch, thread t owns rows 4t..4t+3.
// Straight-line BRANCHLESS body: unconditional clamped loads (no divergent
// guard -> loose vmcnt, full scheduling freedom in one BB), cndmask-based
// quad rotation, no validity masks (BIGE is a fixed point of the update in
// f32; junk cells at j>=S are finite and never reach any valid cell).
// Rolled 4-phase loop (unroll disabled) keeps the body I$-resident.

template <int I> __device__ __forceinline__ float comp(const float4& v) {
    if constexpr (I == 0) return v.x;
    else if constexpr (I == 1) return v.y;
    else if constexpr (I == 2) return v.z;
    else return v.w;
}

__device__ __forceinline__ float4 sel4(bool c, const float4& a, const float4& b) {
    float4 r;
    r.x = c ? a.x : b.x; r.y = c ? a.y : b.y;
    r.z = c ? a.z : b.z; r.w = c ? a.w : b.w;
    return r;
}

__device__ __forceinline__ float cell(float a, float b, float c, float cE) {
    float m = fminf(fminf(a, b), c);                       // v_min3_f32
    float s = EXP2F(m - a) + EXP2F(m - b) + EXP2F(m - c);  // one term is exactly 1
    return cE + m - LOG2F(s);
}

template <int P>
__device__ __forceinline__ void stepf(
    int kk, int t, int t4, const float* __restrict__ Cb,
    int ro0, int ro1, int ro2, int ro3,
    float4& c0, float4& c1, float4& c2, float4& c3,
    float4& n0, float4& n1, float4& n2, float4& n3,
    float4& x0, float4& x1, float4& x2, float4& x3,
    float& d10, float& d11, float& d12, float& d13,
    float& d20, float& d21, float& d22, float& d23)
{
    float pd1 = __shfl_up(d13, 1);
    float pd2 = __shfl_up(d23, 1);
    if (t == 0) { pd1 = BIGE; pd2 = BIGE; }

    // designated row P advances its quad pipeline this step (jp is a multiple of 4)
    const int jp  = kk - t4 - P;
    const int jpc = min(max(jp, 0), S - 12);        // v_med3_i32
    const int roP = (P == 0) ? ro0 : (P == 1) ? ro1 : (P == 2) ? ro2 : ro3;
    const float4 ld = *(const float4*)(Cb + roP + jpc);   // unconditional, clamped

    float4& cP = (P == 0) ? c0 : (P == 1) ? c1 : (P == 2) ? c2 : c3;
    float4& nP = (P == 0) ? n0 : (P == 1) ? n1 : (P == 2) ? n2 : n3;
    float4& xP = (P == 0) ? x0 : (P == 1) ? x1 : (P == 2) ? x2 : x3;
    const bool rot = (jp > 0) && (jp < S);
    cP = sel4(rot, nP, cP);
    nP = sel4(rot, xP, nP);
    xP = ld;

    float e0 = cell(d10, pd1, pd2, comp<(P    ) & 3>(c0) * L2E);
    float e1 = cell(d11, d10, d20, comp<(P + 3) & 3>(c1) * L2E);
    float e2 = cell(d12, d11, d21, comp<(P + 2) & 3>(c2) * L2E);
    float e3 = cell(d13, d12, d22, comp<(P + 1) & 3>(c3) * L2E);

    d20 = d10; d21 = d11; d22 = d12; d23 = d13;
    d10 = e0;  d11 = e1;  d12 = e2;  d13 = e3;
}

__global__ __launch_bounds__(64, 1) void dp_softmin_wave(const float* __restrict__ C,
                                                         float* __restrict__ out) {
    const int b = blockIdx.x;
    const int t = threadIdx.x;
    const float* Cb = C + ((size_t)b << 16);
    const int t4 = 4 * t;

    // element offset of row r's x-quad base: (row<<8) + 8  (x covers columns jp+8..jp+11)
    const int ro0 = ((t4 + 0) << 8) + 8;
    const int ro1 = ((t4 + 1) << 8) + 8;
    const int ro2 = ((t4 + 2) << 8) + 8;
    const int ro3 = ((t4 + 3) << 8) + 8;

    const float* R0 = Cb + ((size_t)(t4 + 0) << 8);
    const float* R1 = Cb + ((size_t)(t4 + 1) << 8);
    const float* R2 = Cb + ((size_t)(t4 + 2) << 8);
    const float* R3 = Cb + ((size_t)(t4 + 3) << 8);

    float4 c0 = *(const float4*)(R0),     c1 = *(const float4*)(R1),
           c2 = *(const float4*)(R2),     c3 = *(const float4*)(R3);
    float4 n0 = *(const float4*)(R0 + 4), n1 = *(const float4*)(R1 + 4),
           n2 = *(const float4*)(R2 + 4), n3 = *(const float4*)(R3 + 4);
    float4 x0 = *(const float4*)(R0 + 8), x1 = *(const float4*)(R1 + 8),
           x2 = *(const float4*)(R2 + 8), x3 = *(const float4*)(R3 + 8);

    float d10 = BIGE, d11 = BIGE, d12 = BIGE, d13 = BIGE;
    float d20 = BIGE, d21 = BIGE, d22 = BIGE, d23 = BIGE;

    if (t == 0) d10 = c0.x * L2E;          // seed D[0][0] = C[0][0]

#define ARGS t, t4, Cb, ro0, ro1, ro2, ro3, c0,c1,c2,c3, n0,n1,n2,n3, x0,x1,x2,x3, \
             d10,d11,d12,d13, d20,d21,d22,d23

    stepf<1>(1, ARGS);
    stepf<2>(2, ARGS);
    stepf<3>(3, ARGS);
#pragma clang loop unroll(disable)
    for (int kb = 4; kb <= 504; kb += 4) {
        stepf<0>(kb + 0, ARGS);
        stepf<1>(kb + 1, ARGS);
        stepf<2>(kb + 2, ARGS);
        stepf<3>(kb + 3, ARGS);
    }
    stepf<0>(508, ARGS);
    stepf<1>(509, ARGS);
    stepf<2>(510, ARGS);
#undef ARGS

    // D[255][255] is thread 63's d13 (E-domain)
    if (t == 63) out[b] = d13 * LN2;
}

extern "C" void kernel_launch(void* const* d_in, const int* in_sizes, int n_in,
                              void* d_out, int out_size, void* d_ws, size_t ws_size,
                              hipStream_t stream) {
    const float* C = (const float*)d_in[0];
    float* out = (float*)d_out;
    dp_softmin_wave<<<512, 64, 0, stream>>>(C, out);
}